// Round 14
// baseline (223.726 us; speedup 1.0000x reference)
//
#include <hip/hip_runtime.h>

// Problem constants (from reference): B=128, D_IN=64, N=50000, NNZ=800000
#define B_    128
#define DIN_  64
#define NN_   50000
#define NNZ_  800000
#define CAP_  64      // slots per column. deg ~ Poisson(16); P(deg>=64) ~ 1e-19.

#define BUCKET_BLOCKS_ 1563  // ceil(800000/512)
#define FUSED_BLOCKS_  2345  // 782 gemm + 1563 bucket, interleave %3
#define GEMM_TILES_    782   // ceil(50000/64)
#define GQ_BLOCKS_     782   // gather: 64 cols per block

// round-to-nearest-even f32 -> bf16 bits
__device__ __forceinline__ unsigned short f2bf(float f) {
    unsigned int u = __float_as_uint(f);
    u += 0x7FFFu + ((u >> 16) & 1u);
    return (unsigned short)(u >> 16);
}

// ---------------------------------------------------------------------------
// FUSED gemm + bucket (round-9 proven structure; round-13 XCD-affinity bucket
// reverted: write-back −26% but 8x re-read cost more, net regression).
// NEW: m is stored QUARTER-MAJOR m_q[4][NN][32] bf16 — each (q,row) is one
// 64B line, so the gather's per-quarter working set is 3.2MB < 4MB/XCD L2.
// ---------------------------------------------------------------------------
__global__ __launch_bounds__(512) void fused_gb(const float* __restrict__ x,
                                                const float* __restrict__ W,
                                                unsigned short* __restrict__ m_q,
                                                const int* __restrict__ rows,
                                                const int* __restrict__ cols,
                                                const float* __restrict__ vals,
                                                int* __restrict__ cnt,
                                                unsigned int* __restrict__ csc) {
    __shared__ float xs_t[DIN_][132];
    const int t = threadIdx.x;
    const int g = blockIdx.x / 3;
    const int r = blockIdx.x % 3;

    if (r != 0) {
        // ---- bucket role ----
        const int bid = 2 * g + (r - 1);
        if (bid >= BUCKET_BLOCKS_) return;
        const int e = bid * 512 + t;
        if (e >= NNZ_) return;
        const int c = cols[e];
        const int pos = atomicAdd(&cnt[c], 1);
        if (pos < CAP_)
            csc[((unsigned int)c << 6) + pos] =
                ((unsigned int)rows[e] << 16) | (unsigned int)f2bf(vals[e]);
        return;
    }

    // ---- gemm role: tile g of 782, coalesced W loads, 8-deep prefetch ----
    for (int i = t; i < B_ * DIN_; i += 512)
        xs_t[i & 63][i >> 6] = x[i];
    __syncthreads();

    const int l  = t & 63;
    const int n  = g * 64 + l;
    const int nc = n < NN_ ? n : NN_ - 1;   // clamped loads; store guarded
    const int b0 = (t >> 6) * 16;           // wave-uniform

    float acc[16];
    #pragma unroll
    for (int j = 0; j < 16; ++j) acc[j] = 0.f;

    const float* Wp = W + nc;
    float wcur[8], wnxt[8];
    #pragma unroll
    for (int q = 0; q < 8; ++q) wcur[q] = Wp[(size_t)q * NN_];

    for (int k = 0; k < DIN_; k += 8) {
        const int kn = k + 8;
        if (kn < DIN_) {
            #pragma unroll
            for (int q = 0; q < 8; ++q) wnxt[q] = Wp[(size_t)(kn + q) * NN_];
        }
        #pragma unroll
        for (int q = 0; q < 8; ++q) {
            const float wv = wcur[q];
            const float4* xp = reinterpret_cast<const float4*>(&xs_t[k + q][b0]);
            const float4 x0 = xp[0], x1 = xp[1], x2 = xp[2], x3 = xp[3];
            acc[0]  += wv * x0.x;  acc[1]  += wv * x0.y;
            acc[2]  += wv * x0.z;  acc[3]  += wv * x0.w;
            acc[4]  += wv * x1.x;  acc[5]  += wv * x1.y;
            acc[6]  += wv * x1.z;  acc[7]  += wv * x1.w;
            acc[8]  += wv * x2.x;  acc[9]  += wv * x2.y;
            acc[10] += wv * x2.z;  acc[11] += wv * x2.w;
            acc[12] += wv * x3.x;  acc[13] += wv * x3.y;
            acc[14] += wv * x3.z;  acc[15] += wv * x3.w;
        }
        #pragma unroll
        for (int q = 0; q < 8; ++q) wcur[q] = wnxt[q];
    }

    if (n < NN_) {
        // quarter-major store: b = b0..b0+15 lives in quarter q = b0>>5,
        // offset off = b0&31 (0 or 16). 32B per thread, 64B line per (q,n).
        const int qq  = b0 >> 5;
        const int off = b0 & 31;
        unsigned int pk[8];
        #pragma unroll
        for (int j = 0; j < 8; ++j)
            pk[j] = (unsigned int)f2bf(acc[2 * j]) |
                    ((unsigned int)f2bf(acc[2 * j + 1]) << 16);
        uint4* op = reinterpret_cast<uint4*>(m_q + ((size_t)qq * NN_ + n) * 32 + off);
        op[0] = make_uint4(pk[0], pk[1], pk[2], pk[3]);
        op[1] = make_uint4(pk[4], pk[5], pk[6], pk[7]);
    }
}

// ---------------------------------------------------------------------------
// gather, L2-resident edition. 4 sequential quarter-passes; per pass the hot
// array is m_q[q] = 3.2MB (fits every XCD's 4MB L2; old layout thrashed at
// 12.8MB -> L3 latency). Block = 256 thr = 4 waves; wave handles 2 columns
// per step (lanes<32 -> c, lanes>=32 -> c+1); per edge one 64B line per
// half-wave. 8-deep predicated unroll (p=0 pad: val bf16=0 -> FMA no-op).
// All 782 blocks co-resident -> quarters stay in loose lockstep.
// ---------------------------------------------------------------------------
__global__ __launch_bounds__(256) void gather_l2(const unsigned short* __restrict__ m_q,
                                                 const int* __restrict__ cnt,
                                                 const unsigned int* __restrict__ csc,
                                                 float* __restrict__ out) {
    __shared__ float tile[32][65];
    const int t    = threadIdx.x;
    const int grp  = t >> 6;          // wave id 0..3
    const int lane = t & 63;
    const int half = lane >> 5;       // 0/1 -> which column of the pair
    const int bl   = lane & 31;       // b within quarter
    const int c0   = blockIdx.x * 64;

    for (int q = 0; q < 4; ++q) {
        const unsigned short* mbase = m_q + (size_t)q * NN_ * 32;

        for (int s = 0; s < 8; ++s) {
            const int c = c0 + s * 8 + grp * 2 + half;
            float acc = 0.f;
            int n = 0;
            const unsigned int* ce = csc;
            if (c < NN_) {
                n = cnt[c]; if (n > CAP_) n = CAP_;
                ce = csc + ((unsigned int)c << 6);
            }
            for (int i = 0; __any(i < n); i += 8) {
                unsigned int  p[8];
                unsigned short mv[8];
                #pragma unroll
                for (int j = 0; j < 8; ++j)
                    p[j] = (i + j < n) ? ce[i + j] : 0u;
                #pragma unroll
                for (int j = 0; j < 8; ++j)
                    mv[j] = mbase[(size_t)(p[j] >> 16) * 32 + bl];
                #pragma unroll
                for (int j = 0; j < 8; ++j)
                    acc += __uint_as_float((unsigned int)mv[j] << 16) *
                           __uint_as_float(p[j] << 16);
            }
            tile[bl][s * 8 + grp * 2 + half] = acc;
        }
        __syncthreads();

        // write-out quarter q: thread t -> row r = t>>3 (b = q*32+r),
        // seg = t&7 (8 cols). 32B stores, 256B contiguous per 8 threads.
        const int r = t >> 3, seg = t & 7;
        const int cbase = c0 + seg * 8;
        const float* tr = &tile[r][seg * 8];
        float* orow = &out[(size_t)(q * 32 + r) * NN_];
        if (cbase + 7 < NN_) {
            float4* op = reinterpret_cast<float4*>(orow + cbase);
            op[0] = make_float4(tr[0], tr[1], tr[2], tr[3]);
            op[1] = make_float4(tr[4], tr[5], tr[6], tr[7]);
        } else {
            for (int j = 0; j < 8; ++j)
                if (cbase + j < NN_) orow[cbase + j] = tr[j];
        }
        __syncthreads();   // tile reused next quarter
    }
}

// ---------------------------------------------------------------------------
// Fallback (tiny ws): recompute m on the fly per edge, atomic into out.
// ---------------------------------------------------------------------------
__global__ __launch_bounds__(256) void scatter_onfly(const float* __restrict__ x,
                                                     const float* __restrict__ W,
                                                     const int* __restrict__ rows,
                                                     const int* __restrict__ cols,
                                                     const float* __restrict__ vals,
                                                     float* __restrict__ out) {
    const unsigned int gid = blockIdx.x * 256u + threadIdx.x;
    const unsigned int e = gid >> 7;
    const unsigned int b = gid & 127u;
    if (e >= NNZ_) return;
    const int   r = rows[e];
    const int   c = cols[e];
    const float v = vals[e];
    float dot = 0.f;
    for (int k = 0; k < DIN_; ++k)
        dot += x[b * DIN_ + k] * W[(size_t)k * NN_ + r];
    atomicAdd(&out[(size_t)b * NN_ + c], dot * v);
}

extern "C" void kernel_launch(void* const* d_in, const int* in_sizes, int n_in,
                              void* d_out, int out_size, void* d_ws, size_t ws_size,
                              hipStream_t stream) {
    const float* x    = (const float*)d_in[0];
    const float* W    = (const float*)d_in[1];
    const int*   rows = (const int*)d_in[2];
    const int*   cols = (const int*)d_in[3];
    const float* vals = (const float*)d_in[4];
    float* out = (float*)d_out;

    const size_t mbf_bytes = (size_t)NN_ * B_ * sizeof(unsigned short); // 12,800,000
    const size_t cnt_bytes = (size_t)NN_ * sizeof(int);                 //    200,000
    const size_t csc_bytes = (size_t)NN_ * CAP_ * sizeof(unsigned int); // 12,800,000
    const size_t need = mbf_bytes + cnt_bytes + csc_bytes;              // ~25.8 MB

    if (ws_size >= need) {
        char* p = (char*)d_ws;
        unsigned short* m_q = (unsigned short*)p;  p += mbf_bytes;
        int*            cnt = (int*)p;             p += cnt_bytes;
        unsigned int*   csc = (unsigned int*)p;

        hipMemsetAsync(cnt, 0, cnt_bytes, stream);
        fused_gb <<<FUSED_BLOCKS_, 512, 0, stream>>>(x, W, m_q, rows, cols, vals, cnt, csc);
        gather_l2<<<GQ_BLOCKS_,    256, 0, stream>>>(m_q, cnt, csc, out);
    } else {
        // Fallback: no scratch — recompute m per edge, atomics into out.
        const int scatter_blocks = (NNZ_ * 128) / 256;
        hipMemsetAsync(out, 0, (size_t)NN_ * B_ * sizeof(float), stream);
        scatter_onfly<<<scatter_blocks, 256, 0, stream>>>(x, W, rows, cols, vals, out);
    }
}